// Round 13
// baseline (934.984 us; speedup 1.0000x reference)
//
#include <hip/hip_runtime.h>
#include <cstdint>

#define BB 8
#define CC 256
#define HH 128
#define WW 128
#define HW (HH * WW)

typedef __attribute__((ext_vector_type(8))) short bf16x8;
typedef __attribute__((ext_vector_type(4))) float f32x4;

// round-to-nearest-even f32 -> bf16 (low 16 bits)
__device__ __forceinline__ uint32_t f2bf(float f) {
    uint32_t u = __float_as_uint(f);
    return (u + 0x7FFFu + ((u >> 16) & 1u)) >> 16;
}
__device__ __forceinline__ float bf2f(uint32_t u) {
    return __uint_as_float(u << 16);
}

// ---------------------------------------------------------------------------
// Setup kernel: pack conv weights into MFMA B-fragment order, bf16.
// Bpre[kt][g][j][e], k = kt*32 + g*8 + e (K padded 98->128),
// j: [0,49) dy, [49,98) dx, [98,147) mask; padded to 160.
// ---------------------------------------------------------------------------
__global__ __launch_bounds__(256) void prep_B(const float* __restrict__ w_off,
                                              uint16_t* __restrict__ Bpre) {
    const int idx = blockIdx.x * 256 + threadIdx.x;
    if (idx >= 4 * 4 * 160 * 8) return;
    const int e  = idx & 7;
    const int t1 = idx >> 3;
    const int j  = t1 % 160;
    const int t2 = t1 / 160;
    const int g  = t2 & 3;
    const int kt = t2 >> 2;
    const int k  = kt * 32 + g * 8 + e;
    uint16_t v = 0;
    if (k < 98 && j < 147) {
        const int ch = (j < 49) ? (2 * j) : ((j < 98) ? (2 * (j - 49) + 1) : j);
        v = (uint16_t)f2bf(w_off[(size_t)ch * 98 + k]);
    }
    Bpre[idx] = v;
}

// ---------------------------------------------------------------------------
// produce_row: channel mean/max reduce of x[b, :, hr, :] -> y2 row (interleaved
// {mean, max} float2). Block-uniform call, 256 threads, contains barriers.
// ---------------------------------------------------------------------------
__device__ __forceinline__ void produce_row(const float* __restrict__ x,
                                            float* __restrict__ y2,
                                            int b, int hr, int t,
                                            float4 (*pls)[32], float4 (*plm)[32]) {
    const int wq = t & 31;       // float4 column
    const int cg = t >> 5;       // channel group 0..7 (32 channels each)
    const float* xb = x + ((size_t)(b * CC + cg * 32) * HH + hr) * WW;

    float4 s = make_float4(0.f, 0.f, 0.f, 0.f);
    float4 m = make_float4(-INFINITY, -INFINITY, -INFINITY, -INFINITY);
    #pragma unroll 4
    for (int i = 0; i < 32; ++i) {
        float4 v = ((const float4*)(xb + (size_t)i * HW))[wq];
        s.x += v.x; s.y += v.y; s.z += v.z; s.w += v.w;
        m.x = fmaxf(m.x, v.x); m.y = fmaxf(m.y, v.y);
        m.z = fmaxf(m.z, v.z); m.w = fmaxf(m.w, v.w);
    }
    pls[cg][wq] = s;
    plm[cg][wq] = m;
    __syncthreads();

    if (t < 32) {
        float4 S = pls[0][t];
        float4 M = plm[0][t];
        #pragma unroll
        for (int g = 1; g < 8; ++g) {
            float4 a = pls[g][t];
            float4 c = plm[g][t];
            S.x += a.x; S.y += a.y; S.z += a.z; S.w += a.w;
            M.x = fmaxf(M.x, c.x); M.y = fmaxf(M.y, c.y);
            M.z = fmaxf(M.z, c.z); M.w = fmaxf(M.w, c.w);
        }
        const float inv = 1.0f / 256.0f;
        float4 o0 = make_float4(S.x * inv, M.x, S.y * inv, M.y);
        float4 o1 = make_float4(S.z * inv, M.z, S.w * inv, M.w);
        float4* yo = (float4*)(y2 + ((size_t)b * HW + (size_t)hr * WW) * 2);
        yo[2 * t]     = o0;
        yo[2 * t + 1] = o1;
    }
    __syncthreads();
}

// ---------------------------------------------------------------------------
// ensure_rows: deadlock-free row-ticket protocol (agent-scope atomics).
// ticket: 0 = unproduced, 1 = claimed by a RUNNING block (its produce path
// has no dependencies -> always completes -> bounded spin), 2 = done.
// Block-uniform call; rowbits is the block's LDS known-done bitmask.
// ---------------------------------------------------------------------------
__device__ __forceinline__ void ensure_rows(
    int lo, int hi, int b, int t,
    const float* __restrict__ x, float* __restrict__ y2,
    uint32_t* __restrict__ tick,
    uint32_t* rowbits, int* action,
    float4 (*pls)[32], float4 (*plm)[32])
{
    // parallel fast pre-check
    if (t <= hi - lo) {
        const int r = lo + t;
        if (!((rowbits[r >> 5] >> (r & 31)) & 1u)) {
            if (__hip_atomic_load(&tick[b * HH + r], __ATOMIC_ACQUIRE,
                                  __HIP_MEMORY_SCOPE_AGENT) == 2u)
                atomicOr(&rowbits[r >> 5], 1u << (r & 31));
        }
    }
    __syncthreads();

    for (int r = lo; r <= hi; ++r) {
        if (!((rowbits[r >> 5] >> (r & 31)) & 1u)) {   // block-uniform
            uint32_t* tk = &tick[b * HH + r];
            if (t == 0) {
                int a = 0;
                uint32_t v = __hip_atomic_load(tk, __ATOMIC_ACQUIRE,
                                               __HIP_MEMORY_SCOPE_AGENT);
                if (v != 2u) {
                    uint32_t exp0 = 0u;
                    if (__hip_atomic_compare_exchange_strong(
                            tk, &exp0, 1u, __ATOMIC_ACQ_REL, __ATOMIC_ACQUIRE,
                            __HIP_MEMORY_SCOPE_AGENT)) {
                        a = 1;                       // we produce it
                    } else {
                        while (__hip_atomic_load(tk, __ATOMIC_ACQUIRE,
                                                 __HIP_MEMORY_SCOPE_AGENT) != 2u)
                            __builtin_amdgcn_s_sleep(8);
                    }
                }
                *action = a;
            }
            __syncthreads();
            if (*action == 1) {
                produce_row(x, y2, b, r, t, pls, plm);
                __threadfence();                     // flush writers' stores
                __syncthreads();
                if (t == 0)
                    __hip_atomic_store(tk, 2u, __ATOMIC_RELEASE,
                                       __HIP_MEMORY_SCOPE_AGENT);
            }
            if (t == 0) rowbits[r >> 5] |= 1u << (r & 31);
            __syncthreads();
        }
    }
}

// ---------------------------------------------------------------------------
// Fused kernel: ticket-produce (mean/max reduce) + MFMA conv + deformable
// sampling + broadcast write. Grid = 4096 blocks (quarter-row), 256 thr.
// Overlaps the x-read stage of late rows with the out-write stage of early
// rows (r12 lesson: serial stage pairs waste half the memory system).
// Lessons kept: no min-waves hint (r3/r4/r6 spills); pre-packed B fragments;
// fused per-block output write (r10/r12).
// ---------------------------------------------------------------------------
__global__ __launch_bounds__(256) void fused_gate(
    const float* __restrict__ x, float* __restrict__ y2,
    uint32_t* __restrict__ tick, const uint16_t* __restrict__ Bpre,
    const float* __restrict__ b_off,
    const float* __restrict__ w_dcn, const float* __restrict__ b_dcn,
    const float* __restrict__ bn_gamma, const float* __restrict__ bn_beta,
    const float* __restrict__ bn_mean, const float* __restrict__ bn_var,
    float* __restrict__ out)
{
    const int bid  = blockIdx.x;        // 4096
    const int rowg = bid >> 2;          // b*128 + h
    const int qpos = (bid & 3) * 32;
    const int b = rowg >> 7;
    const int h = rowg & 127;
    const int t = threadIdx.x;
    const int wv = t >> 6;
    const int l  = t & 63;
    const int mhalf = wv >> 1;
    const int nhalf = wv & 1;
    const bool act = (l < 49);
    const int ls = act ? l : 0;

    __shared__ float4 pls[8][32];          // produce scratch (8 KB)
    __shared__ float4 plm[8][32];
    __shared__ uint32_t patch_pk[7][40];   // bf16x2 {mean,max} window
    __shared__ uint16_t cv[2][16][168];    // conv out bf16 [mhalf][pos][j]
    __shared__ float gate_blk[32];
    __shared__ uint32_t rowbits[4];        // known-produced bitmask
    __shared__ int action;
    __shared__ int wrange[8];              // per-wave row min/max

    if (t < 4) rowbits[t] = 0;
    __syncthreads();

    // ---- phase 1: ensure conv-patch rows, then stage patch ----
    ensure_rows(max(0, h - 3), min(HH - 1, h + 3), b, t, x, y2, tick,
                rowbits, &action, pls, plm);

    const float2* y2b = (const float2*)y2 + (size_t)b * HW;

    for (int i = t; i < 7 * 40; i += 256) {
        const int r  = i / 40;
        const int xi = i % 40;
        const int xx = qpos + xi - 3;
        const int yy = h + r - 3;
        uint32_t v = 0;
        if (yy >= 0 && yy < HH && xx >= 0 && xx < WW) {
            float2 g2 = y2b[yy * WW + xx];
            v = f2bf(g2.x) | (f2bf(g2.y) << 16);
        }
        patch_pk[r][xi] = v;
    }

    // per-lane (tap) sampling constants
    const float b_dy = b_off[2 * ls];
    const float b_dx = b_off[2 * ls + 1];
    const float b_m  = b_off[98 + ls];
    const float wd0 = w_dcn[ls];
    const float wd1 = w_dcn[49 + ls];
    const int kr = ls / 7;
    const int kc = ls % 7;
    const float bscale = bn_gamma[0] * rsqrtf(bn_var[0] + 1e-5f);
    const float gB = (b_dcn[0] - bn_mean[0]) * bscale + bn_beta[0];

    __syncthreads();

    // ---- MFMA conv: 16 positions (mhalf) x 80 channels (nhalf) ----
    const int m = l & 15;
    const int g = l >> 4;
    const int plocal = mhalf * 16 + m;
    const uint16_t* patch_u16 = (const uint16_t*)patch_pk;

    f32x4 acc[5];
    #pragma unroll
    for (int nn = 0; nn < 5; ++nn) acc[nn] = (f32x4){0.f, 0.f, 0.f, 0.f};

    #pragma unroll
    for (int kt = 0; kt < 4; ++kt) {
        union { uint16_t u[8]; bf16x8 v; } af;
        const int K0 = kt * 32 + g * 8;
        #pragma unroll
        for (int e = 0; e < 8; ++e) {
            const int k  = K0 + e;
            const int kk = (k < 98) ? k : 0;
            const int ci = (kk >= 49) ? 1 : 0;
            const int rc = kk - 49 * ci;
            const int r  = rc / 7;
            const int c  = rc - 7 * r;
            const uint16_t val = patch_u16[(r * 40 + plocal + c) * 2 + ci];
            af.u[e] = (k < 98) ? val : (uint16_t)0;
        }
        #pragma unroll
        for (int nn = 0; nn < 5; ++nn) {
            const int j = (nhalf * 5 + nn) * 16 + m;
            const bf16x8 bfr = *(const bf16x8*)(Bpre + (((kt * 4 + g) * 160 + j) << 3));
            acc[nn] = __builtin_amdgcn_mfma_f32_16x16x32_bf16(af.v, bfr, acc[nn], 0, 0, 0);
        }
    }

    #pragma unroll
    for (int nn = 0; nn < 5; ++nn) {
        #pragma unroll
        for (int q = 0; q < 4; ++q) {
            cv[mhalf][g * 4 + q][(nhalf * 5 + nn) * 16 + m] = (uint16_t)f2bf(acc[nn][q]);
        }
    }
    __syncthreads();

    // ---- phase 2: ensure the data-dependent sampling rows ----
    const uint16_t* cvp = &cv[0][0][0];
    {
        int rmin = HH - 1, rmax = 0;
        #pragma unroll
        for (int pi = 0; pi < 8; ++pi) {
            const int pp = wv * 8 + pi;
            const float dyv = bf2f(cvp[pp * 168 + ls]) + b_dy;
            const float fy = (float)(h + kr - 3) + dyv;
            const int iy0 = (int)floorf(fy);
            const int a = min(max(iy0, 0), HH - 1);
            const int c = min(max(iy0 + 1, 0), HH - 1);
            rmin = min(rmin, a);
            rmax = max(rmax, c);
        }
        #pragma unroll
        for (int off = 1; off < 64; off <<= 1) {
            rmin = min(rmin, __shfl_xor(rmin, off));
            rmax = max(rmax, __shfl_xor(rmax, off));
        }
        if (l == 0) { wrange[wv * 2] = rmin; wrange[wv * 2 + 1] = rmax; }
        __syncthreads();
        int grmin = wrange[0], grmax = wrange[1];
        #pragma unroll
        for (int wvi = 1; wvi < 4; ++wvi) {
            grmin = min(grmin, wrange[wvi * 2]);
            grmax = max(grmax, wrange[wvi * 2 + 1]);
        }
        ensure_rows(grmin, grmax, b, t, x, y2, tick,
                    rowbits, &action, pls, plm);
    }

    // ---- sampling: wave wv owns positions [8*wv, 8*wv+8) of the 32 ----
    #pragma unroll 4
    for (int pi = 0; pi < 8; ++pi) {
        const int pp = wv * 8 + pi;
        const int posn = qpos + pp;
        const int cbase = pp * 168;

        const float dyv = bf2f(cvp[cbase + ls])      + b_dy;
        const float dxv = bf2f(cvp[cbase + 49 + ls]) + b_dx;
        const float mv  = bf2f(cvp[cbase + 98 + ls]) + b_m;
        const float mk = 1.0f / (1.0f + __expf(-mv));

        const float fy = (float)(h + kr - 3) + dyv;
        const float fx = (float)(posn + kc - 3) + dxv;
        const float fly = floorf(fy), flx = floorf(fx);
        const int iy0 = (int)fly, ix0 = (int)flx;
        const int iy1 = iy0 + 1,  ix1 = ix0 + 1;
        const float wy1 = fy - fly, wy0 = 1.0f - wy1;
        const float wx1 = fx - flx, wx0 = 1.0f - wx1;

        const float vy0 = (iy0 >= 0 && iy0 < HH) ? 1.0f : 0.0f;
        const float vy1 = (iy1 >= 0 && iy1 < HH) ? 1.0f : 0.0f;
        const float vx0 = (ix0 >= 0 && ix0 < WW) ? 1.0f : 0.0f;
        const float vx1 = (ix1 >= 0 && ix1 < WW) ? 1.0f : 0.0f;

        const int cy0 = min(max(iy0, 0), HH - 1) * WW;
        const int cy1 = min(max(iy1, 0), HH - 1) * WW;
        const int cx0 = min(max(ix0, 0), WW - 1);
        const int cx1 = min(max(ix1, 0), WW - 1);

        const float w00 = wy0 * wx0 * vy0 * vx0;
        const float w01 = wy0 * wx1 * vy0 * vx1;
        const float w10 = wy1 * wx0 * vy1 * vx0;
        const float w11 = wy1 * wx1 * vy1 * vx1;

        const float2 g00 = y2b[cy0 + cx0];
        const float2 g01 = y2b[cy0 + cx1];
        const float2 g10 = y2b[cy1 + cx0];
        const float2 g11 = y2b[cy1 + cx1];

        const float v0s = g00.x * w00 + g01.x * w01 + g10.x * w10 + g11.x * w11;
        const float v1s = g00.y * w00 + g01.y * w01 + g10.y * w10 + g11.y * w11;

        float tval = mk * fmaf(v0s, wd0, v1s * wd1);
        tval = act ? tval : 0.0f;

        float ssum = tval;
        #pragma unroll
        for (int off = 1; off < 64; off <<= 1)
            ssum += __shfl_xor(ssum, off);

        if (l == 0) {
            const float o = ssum * bscale + gB;
            gate_blk[pp] = 1.0f / (1.0f + __expf(-o));
        }
    }

    __syncthreads();

    // ---- fused broadcast write: out[b, :, h, qpos:qpos+32] (32 KB/block) ----
    const size_t ob = (size_t)b * CC * HW + (size_t)h * WW + qpos;
    const f32x4* gb4 = (const f32x4*)gate_blk;
    #pragma unroll
    for (int it = 0; it < 8; ++it) {
        const int idx = it * 256 + t;
        const int c   = idx >> 3;
        const int q4  = idx & 7;
        __builtin_nontemporal_store(gb4[q4], (f32x4*)(out + ob + (size_t)c * HW) + q4);
    }
}

extern "C" void kernel_launch(void* const* d_in, const int* in_sizes, int n_in,
                              void* d_out, int out_size, void* d_ws, size_t ws_size,
                              hipStream_t stream) {
    const float* x        = (const float*)d_in[0];
    const float* w_off    = (const float*)d_in[1];
    const float* b_off    = (const float*)d_in[2];
    const float* w_dcn    = (const float*)d_in[3];
    const float* b_dcn    = (const float*)d_in[4];
    const float* bn_gamma = (const float*)d_in[5];
    const float* bn_beta  = (const float*)d_in[6];
    const float* bn_mean  = (const float*)d_in[7];
    const float* bn_var   = (const float*)d_in[8];
    float* out = (float*)d_out;

    float*    y2   = (float*)d_ws;                                     // 1 MiB
    uint16_t* Bpre = (uint16_t*)((char*)d_ws + (1 << 20));             // 40 KiB
    uint32_t* tick = (uint32_t*)((char*)d_ws + (1 << 20) + (1 << 16)); // 4 KiB

    hipMemsetAsync(tick, 0, BB * HH * sizeof(uint32_t), stream);
    prep_B<<<(4 * 4 * 160 * 8 + 255) / 256, 256, 0, stream>>>(w_off, Bpre);
    fused_gate<<<4 * BB * HH, 256, 0, stream>>>(x, y2, tick, Bpre, b_off,
                                                w_dcn, b_dcn, bn_gamma, bn_beta,
                                                bn_mean, bn_var, out);
}

// Round 14
// 79.268 us; speedup vs baseline: 11.7953x; 11.7953x over previous
//
#include <hip/hip_runtime.h>
#include <cstdint>

#define BB 8
#define CC 256
#define HH 128
#define WW 128
#define HW (HH * WW)

// padded surfaces in d_ws
#define G_STRIDE 130                    // y2g: [130][130] float2, border 1
#define P_ROWS 134                      // y2p: [134][140] u32, halo 3
#define P_STRIDE 140
#define Y2G_BYTES ((size_t)BB * G_STRIDE * G_STRIDE * 8)   // 1,081,600
#define Y2P_BYTES ((size_t)BB * P_ROWS * P_STRIDE * 4)     //   600,320

typedef __attribute__((ext_vector_type(8))) short bf16x8;
typedef __attribute__((ext_vector_type(4))) float f32x4;

// round-to-nearest-even f32 -> bf16 (low 16 bits)
__device__ __forceinline__ uint32_t f2bf(float f) {
    uint32_t u = __float_as_uint(f);
    return (u + 0x7FFFu + ((u >> 16) & 1u)) >> 16;
}
__device__ __forceinline__ float bf2f(uint32_t u) {
    return __uint_as_float(u << 16);
}

// ---------------------------------------------------------------------------
// Setup kernel: pack conv weights into MFMA B-fragment order (bf16), and
// zero the padded y2 surfaces (their borders must be 0; interiors get
// overwritten by reduce_meanmax, which runs after this on the same stream).
// ---------------------------------------------------------------------------
__global__ __launch_bounds__(256) void prep_B(const float* __restrict__ w_off,
                                              uint16_t* __restrict__ Bpre,
                                              uint32_t* __restrict__ zbase) {
    const int gid = blockIdx.x * 256 + threadIdx.x;
    if (gid < 4 * 4 * 160 * 8) {
        const int e  = gid & 7;
        const int t1 = gid >> 3;
        const int j  = t1 % 160;
        const int t2 = t1 / 160;
        const int g  = t2 & 3;
        const int kt = t2 >> 2;
        const int k  = kt * 32 + g * 8 + e;
        uint16_t v = 0;
        if (k < 98 && j < 147) {
            const int ch = (j < 49) ? (2 * j) : ((j < 98) ? (2 * (j - 49) + 1) : j);
            v = (uint16_t)f2bf(w_off[(size_t)ch * 98 + k]);
        }
        Bpre[gid] = v;
    }
    const int ztot = (int)((Y2G_BYTES + Y2P_BYTES) / 4);
    for (int i = gid; i < ztot; i += gridDim.x * 256)
        zbase[i] = 0;
}

// ---------------------------------------------------------------------------
// Kernel A: channel mean & max of x -> padded surfaces.
// y2g[b][h+1][w+1] = {mean, max} float2 (zero border for clamp-free gathers)
// y2p[b][h+3][w+3] = packed bf16x2 (zero halo for bounds-free conv staging)
// One block per (b, h) row; 512 threads.
// ---------------------------------------------------------------------------
__global__ __launch_bounds__(512) void reduce_meanmax(const float* __restrict__ x,
                                                      float* __restrict__ y2g,
                                                      uint32_t* __restrict__ y2p) {
    const int bh = blockIdx.x;
    const int b  = bh >> 7;
    const int h  = bh & 127;
    const int t  = threadIdx.x;
    const int wq = t & 31;       // float4 column: w = wq*4
    const int cg = t >> 5;       // channel group 0..15 (16 channels each)

    const float* xb = x + ((size_t)(b * CC + cg * 16) * HH + h) * WW;

    float4 s = make_float4(0.f, 0.f, 0.f, 0.f);
    float4 m = make_float4(-INFINITY, -INFINITY, -INFINITY, -INFINITY);
    #pragma unroll 4
    for (int i = 0; i < 16; ++i) {
        float4 v = ((const float4*)(xb + (size_t)i * HW))[wq];
        s.x += v.x; s.y += v.y; s.z += v.z; s.w += v.w;
        m.x = fmaxf(m.x, v.x); m.y = fmaxf(m.y, v.y);
        m.z = fmaxf(m.z, v.z); m.w = fmaxf(m.w, v.w);
    }

    __shared__ float4 ls[16][32];
    __shared__ float4 lm[16][32];
    ls[cg][wq] = s;
    lm[cg][wq] = m;
    __syncthreads();

    if (t < 32) {
        float4 S = ls[0][t];
        float4 M = lm[0][t];
        #pragma unroll
        for (int g = 1; g < 16; ++g) {
            float4 a = ls[g][t];
            float4 c = lm[g][t];
            S.x += a.x; S.y += a.y; S.z += a.z; S.w += a.w;
            M.x = fmaxf(M.x, c.x); M.y = fmaxf(M.y, c.y);
            M.z = fmaxf(M.z, c.z); M.w = fmaxf(M.w, c.w);
        }
        const float inv = 1.0f / 256.0f;
        const float mn[4] = {S.x * inv, S.y * inv, S.z * inv, S.w * inv};
        const float mx[4] = {M.x, M.y, M.z, M.w};

        // gather surface: float2 {mean,max} at [b][h+1][4t+q+1]
        float2* gr = (float2*)y2g + ((size_t)b * G_STRIDE + (h + 1)) * G_STRIDE + (4 * t + 1);
        // conv surface: packed bf16x2 at [b][h+3][4t+q+3]
        uint32_t* pr = y2p + ((size_t)(b * P_ROWS) + (h + 3)) * P_STRIDE + (4 * t + 3);
        #pragma unroll
        for (int q = 0; q < 4; ++q) {
            gr[q] = make_float2(mn[q], mx[q]);
            pr[q] = f2bf(mn[q]) | (f2bf(mx[q]) << 16);
        }
    }
}

// ---------------------------------------------------------------------------
// Kernel B: gate compute + fused broadcast write. Grid = 4096 blocks (one per
// quarter-row = 32 positions), 256 threads = 4 waves.
// Phase 1: wave (mhalf, nhalf) computes 16 pos x 5 N-tiles of the MFMA conv
// (A-fragments from bounds-free y2p copy in LDS, B pre-packed); conv out via
// block LDS cv. Phase 2: each wave samples 8 positions tap-per-lane from the
// zero-bordered y2g (clamp-only, no validity masks). Phase 3: block writes
// out[b, :, h, qpos:qpos+32] (32 KB, nontemporal), overlapping other blocks'
// compute.
// Lessons kept: no min-waves hint (r3/r4/r6 spills); no inter-block sync
// (r13: tickets = 935 us); pre-packed B fragments; fused write (r10/r12).
// ---------------------------------------------------------------------------
__global__ __launch_bounds__(256) void deform_gate(
    const float* __restrict__ y2g, const uint32_t* __restrict__ y2p,
    const uint16_t* __restrict__ Bpre,
    const float* __restrict__ b_off,
    const float* __restrict__ w_dcn, const float* __restrict__ b_dcn,
    const float* __restrict__ bn_gamma, const float* __restrict__ bn_beta,
    const float* __restrict__ bn_mean, const float* __restrict__ bn_var,
    float* __restrict__ out)
{
    const int bid  = blockIdx.x;        // 4096
    const int rowg = bid >> 2;          // b*128 + h
    const int qpos = (bid & 3) * 32;
    const int b = rowg >> 7;
    const int h = rowg & 127;
    const int t = threadIdx.x;
    const int wv = t >> 6;
    const int l  = t & 63;
    const int mhalf = wv >> 1;
    const int nhalf = wv & 1;
    const bool act = (l < 49);
    const int ls = act ? l : 0;

    __shared__ uint32_t patch_pk[7][40];   // bf16x2 {mean,max} window
    __shared__ uint16_t cv[2][16][168];    // conv out bf16 [mhalf][pos][j]
    __shared__ float gate_blk[32];

    // ---- stage patch window: straight copy from padded y2p (no bounds) ----
    const uint32_t* y2pb = y2p + (size_t)(b * P_ROWS) * P_STRIDE;
    #pragma unroll
    for (int i = 0; i < 2; ++i) {
        const int idx = i * 256 + t;
        if (idx < 7 * 40) {
            const int r  = idx / 40;
            const int xi = idx % 40;
            patch_pk[r][xi] = y2pb[(h + r) * P_STRIDE + (qpos + xi)];
        }
    }

    // per-lane (tap) sampling constants
    const float b_dy = b_off[2 * ls];
    const float b_dx = b_off[2 * ls + 1];
    const float b_m  = b_off[98 + ls];
    const float wd0 = w_dcn[ls];
    const float wd1 = w_dcn[49 + ls];
    const int kr = ls / 7;
    const int kc = ls % 7;
    const float bscale = bn_gamma[0] * rsqrtf(bn_var[0] + 1e-5f);
    const float gB = (b_dcn[0] - bn_mean[0]) * bscale + bn_beta[0];

    __syncthreads();

    // ---- MFMA conv: 16 positions (mhalf) x 80 channels (nhalf) ----
    const int m = l & 15;
    const int g = l >> 4;
    const int plocal = mhalf * 16 + m;
    const uint16_t* patch_u16 = (const uint16_t*)patch_pk;

    f32x4 acc[5];
    #pragma unroll
    for (int nn = 0; nn < 5; ++nn) acc[nn] = (f32x4){0.f, 0.f, 0.f, 0.f};

    #pragma unroll
    for (int kt = 0; kt < 4; ++kt) {
        union { uint16_t u[8]; bf16x8 v; } af;
        const int K0 = kt * 32 + g * 8;
        #pragma unroll
        for (int e = 0; e < 8; ++e) {
            const int k  = K0 + e;
            const int kk = (k < 98) ? k : 0;
            const int ci = (kk >= 49) ? 1 : 0;
            const int rc = kk - 49 * ci;
            const int r  = rc / 7;
            const int c  = rc - 7 * r;
            const uint16_t val = patch_u16[(r * 40 + plocal + c) * 2 + ci];
            af.u[e] = (k < 98) ? val : (uint16_t)0;
        }
        #pragma unroll
        for (int nn = 0; nn < 5; ++nn) {
            const int j = (nhalf * 5 + nn) * 16 + m;
            const bf16x8 bfr = *(const bf16x8*)(Bpre + (((kt * 4 + g) * 160 + j) << 3));
            acc[nn] = __builtin_amdgcn_mfma_f32_16x16x32_bf16(af.v, bfr, acc[nn], 0, 0, 0);
        }
    }

    #pragma unroll
    for (int nn = 0; nn < 5; ++nn) {
        #pragma unroll
        for (int q = 0; q < 4; ++q) {
            cv[mhalf][g * 4 + q][(nhalf * 5 + nn) * 16 + m] = (uint16_t)f2bf(acc[nn][q]);
        }
    }
    __syncthreads();

    // ---- sampling: wave wv owns positions [8*wv, 8*wv+8); gathers from the
    //      zero-bordered y2g: clamp to [-1,128], +1 index, no validity ops ----
    const float2* y2gb = (const float2*)y2g + (size_t)b * G_STRIDE * G_STRIDE;
    const uint16_t* cvp = &cv[0][0][0];
    #pragma unroll 4
    for (int pi = 0; pi < 8; ++pi) {
        const int pp = wv * 8 + pi;
        const int posn = qpos + pp;
        const int cbase = pp * 168;

        const float dyv = bf2f(cvp[cbase + ls])      + b_dy;
        const float dxv = bf2f(cvp[cbase + 49 + ls]) + b_dx;
        const float mv  = bf2f(cvp[cbase + 98 + ls]) + b_m;
        const float mk = 1.0f / (1.0f + __expf(-mv));

        const float fy = (float)(h + kr - 3) + dyv;
        const float fx = (float)(posn + kc - 3) + dxv;
        const float fly = floorf(fy), flx = floorf(fx);
        const int iy0 = (int)fly, ix0 = (int)flx;
        const float wy1 = fy - fly, wy0 = 1.0f - wy1;
        const float wx1 = fx - flx, wx0 = 1.0f - wx1;

        const int ry0 = min(max(iy0, -1), HH) + 1;       // [0,129]
        const int ry1 = min(max(iy0 + 1, -1), HH) + 1;
        const int cx0 = min(max(ix0, -1), WW) + 1;
        const int cx1 = min(max(ix0 + 1, -1), WW) + 1;

        const float2* row0 = y2gb + ry0 * G_STRIDE;
        const float2* row1 = y2gb + ry1 * G_STRIDE;
        const float2 g00 = row0[cx0];
        const float2 g01 = row0[cx1];
        const float2 g10 = row1[cx0];
        const float2 g11 = row1[cx1];

        const float w00 = wy0 * wx0;
        const float w01 = wy0 * wx1;
        const float w10 = wy1 * wx0;
        const float w11 = wy1 * wx1;

        const float v0s = g00.x * w00 + g01.x * w01 + g10.x * w10 + g11.x * w11;
        const float v1s = g00.y * w00 + g01.y * w01 + g10.y * w10 + g11.y * w11;

        float tval = mk * fmaf(v0s, wd0, v1s * wd1);
        tval = act ? tval : 0.0f;

        float ssum = tval;
        #pragma unroll
        for (int off = 1; off < 64; off <<= 1)
            ssum += __shfl_xor(ssum, off);

        if (l == 0) {
            const float o = ssum * bscale + gB;
            gate_blk[pp] = 1.0f / (1.0f + __expf(-o));
        }
    }

    __syncthreads();

    // ---- fused broadcast write: out[b, :, h, qpos:qpos+32] (32 KB/block) ----
    const size_t ob = (size_t)b * CC * HW + (size_t)h * WW + qpos;
    const f32x4* gb4 = (const f32x4*)gate_blk;
    #pragma unroll
    for (int it = 0; it < 8; ++it) {
        const int idx = it * 256 + t;
        const int c   = idx >> 3;
        const int q4  = idx & 7;
        __builtin_nontemporal_store(gb4[q4], (f32x4*)(out + ob + (size_t)c * HW) + q4);
    }
}

extern "C" void kernel_launch(void* const* d_in, const int* in_sizes, int n_in,
                              void* d_out, int out_size, void* d_ws, size_t ws_size,
                              hipStream_t stream) {
    const float* x        = (const float*)d_in[0];
    const float* w_off    = (const float*)d_in[1];
    const float* b_off    = (const float*)d_in[2];
    const float* w_dcn    = (const float*)d_in[3];
    const float* b_dcn    = (const float*)d_in[4];
    const float* bn_gamma = (const float*)d_in[5];
    const float* bn_beta  = (const float*)d_in[6];
    const float* bn_mean  = (const float*)d_in[7];
    const float* bn_var   = (const float*)d_in[8];
    float* out = (float*)d_out;

    // workspace layout (contiguous so prep_B can zero y2g+y2p in one sweep)
    float*    y2g  = (float*)d_ws;                                  // 1,081,600 B
    uint32_t* y2p  = (uint32_t*)((char*)d_ws + Y2G_BYTES);          //   600,320 B
    uint16_t* Bpre = (uint16_t*)((char*)d_ws + Y2G_BYTES + Y2P_BYTES + 256); // 40 KiB

    prep_B<<<512, 256, 0, stream>>>(w_off, Bpre, (uint32_t*)d_ws);
    reduce_meanmax<<<BB * HH, 512, 0, stream>>>(x, y2g, y2p);
    deform_gate<<<4 * BB * HH, 256, 0, stream>>>(y2g, y2p, Bpre, b_off,
                                                 w_dcn, b_dcn, bn_gamma, bn_beta,
                                                 bn_mean, bn_var, out);
}

// Round 15
// 78.237 us; speedup vs baseline: 11.9507x; 1.0132x over previous
//
#include <hip/hip_runtime.h>
#include <cstdint>

#define BB 8
#define CC 256
#define HH 128
#define WW 128
#define HW (HH * WW)

typedef __attribute__((ext_vector_type(8))) short bf16x8;
typedef __attribute__((ext_vector_type(4))) float f32x4;

// ---------------------------------------------------------------------------
// Kernel A: per-position channel mean & max of x -> y2 (B, H*W, 2) float2
// interleaved {mean, max}. One block per (b, h) row; 512 threads.
// ---------------------------------------------------------------------------
__global__ __launch_bounds__(512) void reduce_meanmax(const float* __restrict__ x,
                                                      float* __restrict__ y2) {
    const int bh = blockIdx.x;
    const int b  = bh >> 7;
    const int h  = bh & 127;
    const int t  = threadIdx.x;
    const int wq = t & 31;       // float4 column: w = wq*4
    const int cg = t >> 5;       // channel group 0..15 (16 channels each)

    const float* xb = x + ((size_t)(b * CC + cg * 16) * HH + h) * WW;

    float4 s = make_float4(0.f, 0.f, 0.f, 0.f);
    float4 m = make_float4(-INFINITY, -INFINITY, -INFINITY, -INFINITY);
    #pragma unroll 4
    for (int i = 0; i < 16; ++i) {
        float4 v = ((const float4*)(xb + (size_t)i * HW))[wq];
        s.x += v.x; s.y += v.y; s.z += v.z; s.w += v.w;
        m.x = fmaxf(m.x, v.x); m.y = fmaxf(m.y, v.y);
        m.z = fmaxf(m.z, v.z); m.w = fmaxf(m.w, v.w);
    }

    __shared__ float4 ls[16][32];
    __shared__ float4 lm[16][32];
    ls[cg][wq] = s;
    lm[cg][wq] = m;
    __syncthreads();

    if (t < 32) {
        float4 S = ls[0][t];
        float4 M = lm[0][t];
        #pragma unroll
        for (int g = 1; g < 16; ++g) {
            float4 a = ls[g][t];
            float4 c = lm[g][t];
            S.x += a.x; S.y += a.y; S.z += a.z; S.w += a.w;
            M.x = fmaxf(M.x, c.x); M.y = fmaxf(M.y, c.y);
            M.z = fmaxf(M.z, c.z); M.w = fmaxf(M.w, c.w);
        }
        const float inv = 1.0f / 256.0f;
        float4 o0 = make_float4(S.x * inv, M.x, S.y * inv, M.y);
        float4 o1 = make_float4(S.z * inv, M.z, S.w * inv, M.w);
        float4* yo = (float4*)(y2 + ((size_t)b * HW + (size_t)h * WW) * 2);
        yo[2 * t]     = o0;
        yo[2 * t + 1] = o1;
    }
}

// round-to-nearest-even f32 -> bf16 (low 16 bits)
__device__ __forceinline__ uint32_t f2bf(float f) {
    uint32_t u = __float_as_uint(f);
    return (u + 0x7FFFu + ((u >> 16) & 1u)) >> 16;
}
__device__ __forceinline__ float bf2f(uint32_t u) {
    return __uint_as_float(u << 16);
}

// ---------------------------------------------------------------------------
// Setup kernel: pack conv weights into MFMA B-fragment order, bf16.
// Bpre[kt][g][j][e], k = kt*32 + g*8 + e (K padded 98->128),
// j: [0,49) dy, [49,98) dx, [98,147) mask; padded to 192 (8-wave N-split).
// ---------------------------------------------------------------------------
__global__ __launch_bounds__(256) void prep_B(const float* __restrict__ w_off,
                                              uint16_t* __restrict__ Bpre) {
    const int idx = blockIdx.x * 256 + threadIdx.x;
    if (idx >= 4 * 4 * 192 * 8) return;
    const int e  = idx & 7;
    const int t1 = idx >> 3;
    const int j  = t1 % 192;
    const int t2 = t1 / 192;
    const int g  = t2 & 3;
    const int kt = t2 >> 2;
    const int k  = kt * 32 + g * 8 + e;
    uint16_t v = 0;
    if (k < 98 && j < 147) {
        const int ch = (j < 49) ? (2 * j) : ((j < 98) ? (2 * (j - 49) + 1) : j);
        v = (uint16_t)f2bf(w_off[(size_t)ch * 98 + k]);
    }
    Bpre[idx] = v;
}

// ---------------------------------------------------------------------------
// Kernel B: gate compute + fused broadcast write. Grid = 4096 blocks (one per
// quarter-row = 32 positions), 512 threads = 8 waves.
// Wave (mhalf, ngrp) computes 16 pos x 3 N-tiles (N padded to 192) of the
// MFMA conv -> acc[3] = 12 VGPR (r15 goal: total VGPR <= 64 -> 32 waves/CU
// tier, 2x the latency hiding of r12's 4-wave/acc[5] split). Conv out shared
// via LDS cv; each wave then samples 4 positions tap-per-lane; block writes
// out[b, :, h, qpos:qpos+32] (32 KB, nontemporal).
// Lessons kept: no min-waves hint (r3/r4/r6 spills); no inter-block sync
// (r13); pre-packed B fragments (r9); fused write (r12); inline-bounds
// staging, not padded surfaces (r14 regression).
// ---------------------------------------------------------------------------
__global__ __launch_bounds__(512) void deform_gate(
    const float* __restrict__ y2, const uint16_t* __restrict__ Bpre,
    const float* __restrict__ b_off,
    const float* __restrict__ w_dcn, const float* __restrict__ b_dcn,
    const float* __restrict__ bn_gamma, const float* __restrict__ bn_beta,
    const float* __restrict__ bn_mean, const float* __restrict__ bn_var,
    float* __restrict__ out)
{
    const int bid  = blockIdx.x;        // 4096
    const int rowg = bid >> 2;          // b*128 + h
    const int qpos = (bid & 3) * 32;
    const int b = rowg >> 7;
    const int h = rowg & 127;
    const int t = threadIdx.x;
    const int wv = t >> 6;              // 0..7
    const int l  = t & 63;
    const int mhalf = wv >> 2;          // 16-position half
    const int ngrp  = wv & 3;           // 3-tile N group
    const bool act = (l < 49);
    const int ls = act ? l : 0;

    __shared__ uint32_t patch_pk[7][40];   // bf16x2 {mean,max} window
    __shared__ uint16_t cv[2][16][184];    // conv out bf16 [mhalf][pos][j]
    __shared__ float gate_blk[32];

    const float2* y2b = (const float2*)y2 + (size_t)b * HW;

    // ---- stage the zero-padded patch window (280 u32, 512 threads) ----
    if (t < 7 * 40) {
        const int r  = t / 40;
        const int xi = t % 40;
        const int xx = qpos + xi - 3;
        const int yy = h + r - 3;
        uint32_t v = 0;
        if (yy >= 0 && yy < HH && xx >= 0 && xx < WW) {
            float2 g2 = y2b[yy * WW + xx];
            v = f2bf(g2.x) | (f2bf(g2.y) << 16);
        }
        patch_pk[r][xi] = v;
    }

    // per-lane (tap) sampling constants
    const float b_dy = b_off[2 * ls];
    const float b_dx = b_off[2 * ls + 1];
    const float b_m  = b_off[98 + ls];
    const float wd0 = w_dcn[ls];
    const float wd1 = w_dcn[49 + ls];
    const int kr = ls / 7;
    const int kc = ls % 7;
    const float bscale = bn_gamma[0] * rsqrtf(bn_var[0] + 1e-5f);
    const float gB = (b_dcn[0] - bn_mean[0]) * bscale + bn_beta[0];

    __syncthreads();

    // ---- MFMA conv: 16 positions (mhalf) x 48 channels (ngrp: 3 tiles) ----
    const int m = l & 15;
    const int g = l >> 4;
    const int plocal = mhalf * 16 + m;
    const uint16_t* patch_u16 = (const uint16_t*)patch_pk;

    f32x4 acc[3];
    #pragma unroll
    for (int nn = 0; nn < 3; ++nn) acc[nn] = (f32x4){0.f, 0.f, 0.f, 0.f};

    #pragma unroll
    for (int kt = 0; kt < 4; ++kt) {
        union { uint16_t u[8]; bf16x8 v; } af;
        const int K0 = kt * 32 + g * 8;
        #pragma unroll
        for (int e = 0; e < 8; ++e) {
            const int k  = K0 + e;
            const int kk = (k < 98) ? k : 0;
            const int ci = (kk >= 49) ? 1 : 0;
            const int rc = kk - 49 * ci;
            const int r  = rc / 7;
            const int c  = rc - 7 * r;
            const uint16_t val = patch_u16[(r * 40 + plocal + c) * 2 + ci];
            af.u[e] = (k < 98) ? val : (uint16_t)0;
        }
        #pragma unroll
        for (int nn = 0; nn < 3; ++nn) {
            const int j = (ngrp * 3 + nn) * 16 + m;
            const bf16x8 bfr = *(const bf16x8*)(Bpre + (((kt * 4 + g) * 192 + j) << 3));
            acc[nn] = __builtin_amdgcn_mfma_f32_16x16x32_bf16(af.v, bfr, acc[nn], 0, 0, 0);
        }
    }

    // ---- C -> cv (bf16): row = g*4+q (pos offset), col = j; skip pad tile 11 ----
    #pragma unroll
    for (int nn = 0; nn < 3; ++nn) {
        const int nt = ngrp * 3 + nn;
        if (nt <= 10) {
            #pragma unroll
            for (int q = 0; q < 4; ++q) {
                cv[mhalf][g * 4 + q][nt * 16 + m] = (uint16_t)f2bf(acc[nn][q]);
            }
        }
    }
    __syncthreads();

    // ---- sampling: wave wv owns positions [4*wv, 4*wv+4) of the 32 ----
    const uint16_t* cvp = &cv[0][0][0];
    #pragma unroll
    for (int pi = 0; pi < 4; ++pi) {
        const int pp = wv * 4 + pi;
        const int posn = qpos + pp;
        const int cbase = pp * 184;          // cv flat [32][184]

        const float dyv = bf2f(cvp[cbase + ls])      + b_dy;
        const float dxv = bf2f(cvp[cbase + 49 + ls]) + b_dx;
        const float mv  = bf2f(cvp[cbase + 98 + ls]) + b_m;
        const float mk = 1.0f / (1.0f + __expf(-mv));

        const float fy = (float)(h + kr - 3) + dyv;
        const float fx = (float)(posn + kc - 3) + dxv;
        const float fly = floorf(fy), flx = floorf(fx);
        const int iy0 = (int)fly, ix0 = (int)flx;
        const int iy1 = iy0 + 1,  ix1 = ix0 + 1;
        const float wy1 = fy - fly, wy0 = 1.0f - wy1;
        const float wx1 = fx - flx, wx0 = 1.0f - wx1;

        const float vy0 = (iy0 >= 0 && iy0 < HH) ? 1.0f : 0.0f;
        const float vy1 = (iy1 >= 0 && iy1 < HH) ? 1.0f : 0.0f;
        const float vx0 = (ix0 >= 0 && ix0 < WW) ? 1.0f : 0.0f;
        const float vx1 = (ix1 >= 0 && ix1 < WW) ? 1.0f : 0.0f;

        const int cy0 = min(max(iy0, 0), HH - 1) * WW;
        const int cy1 = min(max(iy1, 0), HH - 1) * WW;
        const int cx0 = min(max(ix0, 0), WW - 1);
        const int cx1 = min(max(ix1, 0), WW - 1);

        const float w00 = wy0 * wx0 * vy0 * vx0;
        const float w01 = wy0 * wx1 * vy0 * vx1;
        const float w10 = wy1 * wx0 * vy1 * vx0;
        const float w11 = wy1 * wx1 * vy1 * vx1;

        const float2 g00 = y2b[cy0 + cx0];
        const float2 g01 = y2b[cy0 + cx1];
        const float2 g10 = y2b[cy1 + cx0];
        const float2 g11 = y2b[cy1 + cx1];

        const float v0s = g00.x * w00 + g01.x * w01 + g10.x * w10 + g11.x * w11;
        const float v1s = g00.y * w00 + g01.y * w01 + g10.y * w10 + g11.y * w11;

        float tval = mk * fmaf(v0s, wd0, v1s * wd1);
        tval = act ? tval : 0.0f;

        float ssum = tval;
        #pragma unroll
        for (int off = 1; off < 64; off <<= 1)
            ssum += __shfl_xor(ssum, off);

        if (l == 0) {
            const float o = ssum * bscale + gB;
            gate_blk[pp] = 1.0f / (1.0f + __expf(-o));
        }
    }

    __syncthreads();

    // ---- fused broadcast write: out[b, :, h, qpos:qpos+32] (32 KB/block) ----
    const size_t ob = (size_t)b * CC * HW + (size_t)h * WW + qpos;
    const f32x4* gb4 = (const f32x4*)gate_blk;
    #pragma unroll
    for (int it = 0; it < 4; ++it) {
        const int idx = it * 512 + t;
        const int c   = idx >> 3;
        const int q4  = idx & 7;
        __builtin_nontemporal_store(gb4[q4], (f32x4*)(out + ob + (size_t)c * HW) + q4);
    }
}

extern "C" void kernel_launch(void* const* d_in, const int* in_sizes, int n_in,
                              void* d_out, int out_size, void* d_ws, size_t ws_size,
                              hipStream_t stream) {
    const float* x        = (const float*)d_in[0];
    const float* w_off    = (const float*)d_in[1];
    const float* b_off    = (const float*)d_in[2];
    const float* w_dcn    = (const float*)d_in[3];
    const float* b_dcn    = (const float*)d_in[4];
    const float* bn_gamma = (const float*)d_in[5];
    const float* bn_beta  = (const float*)d_in[6];
    const float* bn_mean  = (const float*)d_in[7];
    const float* bn_var   = (const float*)d_in[8];
    float* out = (float*)d_out;

    float*    y2   = (float*)d_ws;                              // 1 MiB
    uint16_t* Bpre = (uint16_t*)((char*)d_ws + (1 << 20));      // 48 KiB

    prep_B<<<(4 * 4 * 192 * 8 + 255) / 256, 256, 0, stream>>>(w_off, Bpre);
    reduce_meanmax<<<BB * HH, 512, 0, stream>>>(x, y2);
    deform_gate<<<4 * BB * HH, 512, 0, stream>>>(y2, Bpre, b_off, w_dcn, b_dcn,
                                                 bn_gamma, bn_beta, bn_mean, bn_var,
                                                 out);
}

// Round 16
// 76.142 us; speedup vs baseline: 12.2795x; 1.0275x over previous
//
#include <hip/hip_runtime.h>
#include <cstdint>

#define BB 8
#define CC 256
#define HH 128
#define WW 128
#define HW (HH * WW)

typedef __attribute__((ext_vector_type(8))) short bf16x8;
typedef __attribute__((ext_vector_type(4))) float f32x4;

// ---------------------------------------------------------------------------
// Kernel A: per-position channel mean & max of x -> y2 (B, H*W, 2) float2
// interleaved {mean, max}. One block per (b, h) row; 512 threads.
// ---------------------------------------------------------------------------
__global__ __launch_bounds__(512) void reduce_meanmax(const float* __restrict__ x,
                                                      float* __restrict__ y2) {
    const int bh = blockIdx.x;
    const int b  = bh >> 7;
    const int h  = bh & 127;
    const int t  = threadIdx.x;
    const int wq = t & 31;       // float4 column: w = wq*4
    const int cg = t >> 5;       // channel group 0..15 (16 channels each)

    const float* xb = x + ((size_t)(b * CC + cg * 16) * HH + h) * WW;

    float4 s = make_float4(0.f, 0.f, 0.f, 0.f);
    float4 m = make_float4(-INFINITY, -INFINITY, -INFINITY, -INFINITY);
    #pragma unroll 4
    for (int i = 0; i < 16; ++i) {
        float4 v = ((const float4*)(xb + (size_t)i * HW))[wq];
        s.x += v.x; s.y += v.y; s.z += v.z; s.w += v.w;
        m.x = fmaxf(m.x, v.x); m.y = fmaxf(m.y, v.y);
        m.z = fmaxf(m.z, v.z); m.w = fmaxf(m.w, v.w);
    }

    __shared__ float4 ls[16][32];
    __shared__ float4 lm[16][32];
    ls[cg][wq] = s;
    lm[cg][wq] = m;
    __syncthreads();

    if (t < 32) {
        float4 S = ls[0][t];
        float4 M = lm[0][t];
        #pragma unroll
        for (int g = 1; g < 16; ++g) {
            float4 a = ls[g][t];
            float4 c = lm[g][t];
            S.x += a.x; S.y += a.y; S.z += a.z; S.w += a.w;
            M.x = fmaxf(M.x, c.x); M.y = fmaxf(M.y, c.y);
            M.z = fmaxf(M.z, c.z); M.w = fmaxf(M.w, c.w);
        }
        const float inv = 1.0f / 256.0f;
        float4 o0 = make_float4(S.x * inv, M.x, S.y * inv, M.y);
        float4 o1 = make_float4(S.z * inv, M.z, S.w * inv, M.w);
        float4* yo = (float4*)(y2 + ((size_t)b * HW + (size_t)h * WW) * 2);
        yo[2 * t]     = o0;
        yo[2 * t + 1] = o1;
    }
}

// round-to-nearest-even f32 -> bf16 (low 16 bits)
__device__ __forceinline__ uint32_t f2bf(float f) {
    uint32_t u = __float_as_uint(f);
    return (u + 0x7FFFu + ((u >> 16) & 1u)) >> 16;
}
__device__ __forceinline__ float bf2f(uint32_t u) {
    return __uint_as_float(u << 16);
}

// ---------------------------------------------------------------------------
// Setup kernel: pack conv weights into MFMA B-fragment order, bf16.
// Bpre[kt][g][j][e], k = kt*32 + g*8 + e (K padded 98->128),
// j: [0,49) dy, [49,98) dx, [98,147) mask; padded to 160.
// ---------------------------------------------------------------------------
__global__ __launch_bounds__(256) void prep_B(const float* __restrict__ w_off,
                                              uint16_t* __restrict__ Bpre) {
    const int idx = blockIdx.x * 256 + threadIdx.x;
    if (idx >= 4 * 4 * 160 * 8) return;
    const int e  = idx & 7;
    const int t1 = idx >> 3;
    const int j  = t1 % 160;
    const int t2 = t1 / 160;
    const int g  = t2 & 3;
    const int kt = t2 >> 2;
    const int k  = kt * 32 + g * 8 + e;
    uint16_t v = 0;
    if (k < 98 && j < 147) {
        const int ch = (j < 49) ? (2 * j) : ((j < 98) ? (2 * (j - 49) + 1) : j);
        v = (uint16_t)f2bf(w_off[(size_t)ch * 98 + k]);
    }
    Bpre[idx] = v;
}

// ---------------------------------------------------------------------------
// Kernel B: gate compute + fused broadcast write. Grid = 4096 blocks (one per
// quarter-row = 32 positions), 256 threads = 4 waves.
// Phase 1: wave (mhalf, nhalf) computes 16 pos x 5 N-tiles of the MFMA conv;
// conv out shared via block LDS cv. Phase 2: each wave samples 8 positions
// tap-per-lane -> gate_blk[32]. Phase 3: block writes out[b,:,h,qpos:qpos+32]
// (32 KB) with PLAIN stores -- they ack at L2 (~35 TB/s), so the wave retires
// fast and the L2->HBM writeback overlaps later blocks' compute. r12's
// nontemporal stores bypassed L2 and serialized each block's write tail at
// HBM rate while holding residency (r16 single-variable change).
// Lessons kept: no min-waves hint (r3/r4/r6 spills); no inter-block sync
// (r13); pre-packed B fragments (r9); fused write (r12); inline-bounds
// staging (r14 regression); 4-wave/256-thread split (r15 regression).
// ---------------------------------------------------------------------------
__global__ __launch_bounds__(256) void deform_gate(
    const float* __restrict__ y2, const uint16_t* __restrict__ Bpre,
    const float* __restrict__ b_off,
    const float* __restrict__ w_dcn, const float* __restrict__ b_dcn,
    const float* __restrict__ bn_gamma, const float* __restrict__ bn_beta,
    const float* __restrict__ bn_mean, const float* __restrict__ bn_var,
    float* __restrict__ out)
{
    const int bid  = blockIdx.x;        // 4096
    const int rowg = bid >> 2;          // b*128 + h
    const int qpos = (bid & 3) * 32;
    const int b = rowg >> 7;
    const int h = rowg & 127;
    const int t = threadIdx.x;
    const int wv = t >> 6;
    const int l  = t & 63;
    const int mhalf = wv >> 1;
    const int nhalf = wv & 1;
    const bool act = (l < 49);
    const int ls = act ? l : 0;

    __shared__ uint32_t patch_pk[7][40];   // bf16x2 {mean,max} window
    __shared__ uint16_t cv[2][16][168];    // conv out bf16 [mhalf][pos][j]
    __shared__ float gate_blk[32];

    const float2* y2b = (const float2*)y2 + (size_t)b * HW;

    // ---- stage the zero-padded patch window ----
    for (int i = t; i < 7 * 40; i += 256) {
        const int r  = i / 40;
        const int xi = i % 40;
        const int xx = qpos + xi - 3;
        const int yy = h + r - 3;
        uint32_t v = 0;
        if (yy >= 0 && yy < HH && xx >= 0 && xx < WW) {
            float2 g2 = y2b[yy * WW + xx];
            v = f2bf(g2.x) | (f2bf(g2.y) << 16);
        }
        patch_pk[r][xi] = v;
    }

    // per-lane (tap) sampling constants
    const float b_dy = b_off[2 * ls];
    const float b_dx = b_off[2 * ls + 1];
    const float b_m  = b_off[98 + ls];
    const float wd0 = w_dcn[ls];
    const float wd1 = w_dcn[49 + ls];
    const int kr = ls / 7;
    const int kc = ls % 7;
    const float bscale = bn_gamma[0] * rsqrtf(bn_var[0] + 1e-5f);
    const float gB = (b_dcn[0] - bn_mean[0]) * bscale + bn_beta[0];

    __syncthreads();

    // ---- MFMA conv: 16 positions (mhalf) x 80 channels (nhalf) ----
    const int m = l & 15;
    const int g = l >> 4;
    const int plocal = mhalf * 16 + m;
    const uint16_t* patch_u16 = (const uint16_t*)patch_pk;

    f32x4 acc[5];
    #pragma unroll
    for (int nn = 0; nn < 5; ++nn) acc[nn] = (f32x4){0.f, 0.f, 0.f, 0.f};

    #pragma unroll
    for (int kt = 0; kt < 4; ++kt) {
        union { uint16_t u[8]; bf16x8 v; } af;
        const int K0 = kt * 32 + g * 8;
        #pragma unroll
        for (int e = 0; e < 8; ++e) {
            const int k  = K0 + e;
            const int kk = (k < 98) ? k : 0;
            const int ci = (kk >= 49) ? 1 : 0;
            const int rc = kk - 49 * ci;
            const int r  = rc / 7;
            const int c  = rc - 7 * r;
            const uint16_t val = patch_u16[(r * 40 + plocal + c) * 2 + ci];
            af.u[e] = (k < 98) ? val : (uint16_t)0;
        }
        #pragma unroll
        for (int nn = 0; nn < 5; ++nn) {
            const int j = (nhalf * 5 + nn) * 16 + m;
            const bf16x8 bfr = *(const bf16x8*)(Bpre + (((kt * 4 + g) * 160 + j) << 3));
            acc[nn] = __builtin_amdgcn_mfma_f32_16x16x32_bf16(af.v, bfr, acc[nn], 0, 0, 0);
        }
    }

    #pragma unroll
    for (int nn = 0; nn < 5; ++nn) {
        #pragma unroll
        for (int q = 0; q < 4; ++q) {
            cv[mhalf][g * 4 + q][(nhalf * 5 + nn) * 16 + m] = (uint16_t)f2bf(acc[nn][q]);
        }
    }
    __syncthreads();

    // ---- sampling: wave wv owns positions [8*wv, 8*wv+8) of the 32 ----
    const uint16_t* cvp = &cv[0][0][0];
    #pragma unroll 4
    for (int pi = 0; pi < 8; ++pi) {
        const int pp = wv * 8 + pi;
        const int posn = qpos + pp;
        const int cbase = pp * 168;

        const float dyv = bf2f(cvp[cbase + ls])      + b_dy;
        const float dxv = bf2f(cvp[cbase + 49 + ls]) + b_dx;
        const float mv  = bf2f(cvp[cbase + 98 + ls]) + b_m;
        const float mk = 1.0f / (1.0f + __expf(-mv));

        const float fy = (float)(h + kr - 3) + dyv;
        const float fx = (float)(posn + kc - 3) + dxv;
        const float fly = floorf(fy), flx = floorf(fx);
        const int iy0 = (int)fly, ix0 = (int)flx;
        const int iy1 = iy0 + 1,  ix1 = ix0 + 1;
        const float wy1 = fy - fly, wy0 = 1.0f - wy1;
        const float wx1 = fx - flx, wx0 = 1.0f - wx1;

        const float vy0 = (iy0 >= 0 && iy0 < HH) ? 1.0f : 0.0f;
        const float vy1 = (iy1 >= 0 && iy1 < HH) ? 1.0f : 0.0f;
        const float vx0 = (ix0 >= 0 && ix0 < WW) ? 1.0f : 0.0f;
        const float vx1 = (ix1 >= 0 && ix1 < WW) ? 1.0f : 0.0f;

        const int cy0 = min(max(iy0, 0), HH - 1) * WW;
        const int cy1 = min(max(iy1, 0), HH - 1) * WW;
        const int cx0 = min(max(ix0, 0), WW - 1);
        const int cx1 = min(max(ix1, 0), WW - 1);

        const float w00 = wy0 * wx0 * vy0 * vx0;
        const float w01 = wy0 * wx1 * vy0 * vx1;
        const float w10 = wy1 * wx0 * vy1 * vx0;
        const float w11 = wy1 * wx1 * vy1 * vx1;

        const float2 g00 = y2b[cy0 + cx0];
        const float2 g01 = y2b[cy0 + cx1];
        const float2 g10 = y2b[cy1 + cx0];
        const float2 g11 = y2b[cy1 + cx1];

        const float v0s = g00.x * w00 + g01.x * w01 + g10.x * w10 + g11.x * w11;
        const float v1s = g00.y * w00 + g01.y * w01 + g10.y * w10 + g11.y * w11;

        float tval = mk * fmaf(v0s, wd0, v1s * wd1);
        tval = act ? tval : 0.0f;

        float ssum = tval;
        #pragma unroll
        for (int off = 1; off < 64; off <<= 1)
            ssum += __shfl_xor(ssum, off);

        if (l == 0) {
            const float o = ssum * bscale + gB;
            gate_blk[pp] = 1.0f / (1.0f + __expf(-o));
        }
    }

    __syncthreads();

    // ---- fused broadcast write: out[b, :, h, qpos:qpos+32] (32 KB/block),
    //      PLAIN stores (ack at L2; writeback overlaps later blocks) ----
    const size_t ob = (size_t)b * CC * HW + (size_t)h * WW + qpos;
    const f32x4* gb4 = (const f32x4*)gate_blk;
    #pragma unroll
    for (int it = 0; it < 8; ++it) {
        const int idx = it * 256 + t;
        const int c   = idx >> 3;
        const int q4  = idx & 7;
        ((f32x4*)(out + ob + (size_t)c * HW))[q4] = gb4[q4];
    }
}

extern "C" void kernel_launch(void* const* d_in, const int* in_sizes, int n_in,
                              void* d_out, int out_size, void* d_ws, size_t ws_size,
                              hipStream_t stream) {
    const float* x        = (const float*)d_in[0];
    const float* w_off    = (const float*)d_in[1];
    const float* b_off    = (const float*)d_in[2];
    const float* w_dcn    = (const float*)d_in[3];
    const float* b_dcn    = (const float*)d_in[4];
    const float* bn_gamma = (const float*)d_in[5];
    const float* bn_beta  = (const float*)d_in[6];
    const float* bn_mean  = (const float*)d_in[7];
    const float* bn_var   = (const float*)d_in[8];
    float* out = (float*)d_out;

    float*    y2   = (float*)d_ws;                              // 1 MiB
    uint16_t* Bpre = (uint16_t*)((char*)d_ws + (1 << 20));      // 40 KiB

    prep_B<<<(4 * 4 * 160 * 8 + 255) / 256, 256, 0, stream>>>(w_off, Bpre);
    reduce_meanmax<<<BB * HH, 512, 0, stream>>>(x, y2);
    deform_gate<<<4 * BB * HH, 256, 0, stream>>>(y2, Bpre, b_off, w_dcn, b_dcn,
                                                 bn_gamma, bn_beta, bn_mean, bn_var,
                                                 out);
}

// Round 17
// 69.120 us; speedup vs baseline: 13.5270x; 1.1016x over previous
//
#include <hip/hip_runtime.h>
#include <cstdint>

#define BB 8
#define CC 256
#define HH 128
#define WW 128
#define HW (HH * WW)

typedef __attribute__((ext_vector_type(8))) short bf16x8;
typedef __attribute__((ext_vector_type(4))) float f32x4;

// round-to-nearest-even f32 -> bf16 (low 16 bits)
__device__ __forceinline__ uint32_t f2bf(float f) {
    uint32_t u = __float_as_uint(f);
    return (u + 0x7FFFu + ((u >> 16) & 1u)) >> 16;
}
__device__ __forceinline__ float bf2f(uint32_t u) {
    return __uint_as_float(u << 16);
}

// ---------------------------------------------------------------------------
// Kernel A: per-position channel mean & max of x -> y2 (B, H*W, 2) float2.
// Also folds the B-fragment pre-pack (20 elements per block, threads 0..19):
// saves a separate prep launch (~2.5 us).
// Bpre layout [grp][j][e] (grp = kt*4+g = ci*7+r): padded-K im2col order —
// k_pad = grp*8 + e, real weight at k = ci*49 + r*7 + e for e<7; e==7 and
// grp>=14 are ZERO (these kill the A-side pad garbage: finite*0 = 0).
// ---------------------------------------------------------------------------
__global__ __launch_bounds__(512) void reduce_meanmax(const float* __restrict__ x,
                                                      float* __restrict__ y2,
                                                      const float* __restrict__ w_off,
                                                      uint16_t* __restrict__ Bpre) {
    const int bh = blockIdx.x;
    const int b  = bh >> 7;
    const int h  = bh & 127;
    const int t  = threadIdx.x;

    // ---- folded prep_B: 1024 blocks x 20 = 20480 = 16*160*8 ----
    if (t < 20) {
        const int idx = bh * 20 + t;
        const int e   = idx & 7;
        const int t1  = idx >> 3;
        const int j   = t1 % 160;
        const int grp = t1 / 160;          // 0..15
        uint16_t v = 0;
        if (grp < 14 && e < 7 && j < 147) {
            const int ci = grp / 7, r = grp % 7;
            const int ch = (j < 49) ? (2 * j) : ((j < 98) ? (2 * (j - 49) + 1) : j);
            v = (uint16_t)f2bf(w_off[(size_t)ch * 98 + ci * 49 + r * 7 + e]);
        }
        Bpre[idx] = v;
    }

    const int wq = t & 31;       // float4 column: w = wq*4
    const int cg = t >> 5;       // channel group 0..15 (16 channels each)
    const float* xb = x + ((size_t)(b * CC + cg * 16) * HH + h) * WW;

    float4 s = make_float4(0.f, 0.f, 0.f, 0.f);
    float4 m = make_float4(-INFINITY, -INFINITY, -INFINITY, -INFINITY);
    #pragma unroll 4
    for (int i = 0; i < 16; ++i) {
        float4 v = ((const float4*)(xb + (size_t)i * HW))[wq];
        s.x += v.x; s.y += v.y; s.z += v.z; s.w += v.w;
        m.x = fmaxf(m.x, v.x); m.y = fmaxf(m.y, v.y);
        m.z = fmaxf(m.z, v.z); m.w = fmaxf(m.w, v.w);
    }

    __shared__ float4 ls[16][32];
    __shared__ float4 lm[16][32];
    ls[cg][wq] = s;
    lm[cg][wq] = m;
    __syncthreads();

    if (t < 32) {
        float4 S = ls[0][t];
        float4 M = lm[0][t];
        #pragma unroll
        for (int g = 1; g < 16; ++g) {
            float4 a = ls[g][t];
            float4 c = lm[g][t];
            S.x += a.x; S.y += a.y; S.z += a.z; S.w += a.w;
            M.x = fmaxf(M.x, c.x); M.y = fmaxf(M.y, c.y);
            M.z = fmaxf(M.z, c.z); M.w = fmaxf(M.w, c.w);
        }
        const float inv = 1.0f / 256.0f;
        float4 o0 = make_float4(S.x * inv, M.x, S.y * inv, M.y);
        float4 o1 = make_float4(S.z * inv, M.z, S.w * inv, M.w);
        float4* yo = (float4*)(y2 + ((size_t)b * HW + (size_t)h * WW) * 2);
        yo[2 * t]     = o0;
        yo[2 * t + 1] = o1;
    }
}

// ---------------------------------------------------------------------------
// Kernel B: gate compute + fused broadcast write. Grid = 4096 blocks (one per
// quarter-row = 32 positions), 256 threads = 4 waves.
// A-fragments now come from DE-INTERLEAVED padded-K planes patch2[16][48]
// (grp = ci*7+r): 8 consecutive u16 per fragment -> 5 dword-aligned LDS dword
// reads + 4 funnel shifts, replacing r12's 96 ds_read_u16 + ~100 VALU per
// wave (the dominant latency chain). Pad element e=7 / grp>=14 are zero in B.
// Lessons kept: no min-waves hint (r3/r4/r6 spills); no inter-block sync
// (r13); 4-wave/256-thread split (r15 regression); NT stores (r12 best, r16
// plain-store test was neutral-worse); inline-bounds staging (r14).
// ---------------------------------------------------------------------------
__global__ __launch_bounds__(256) void deform_gate(
    const float* __restrict__ y2, const uint16_t* __restrict__ Bpre,
    const float* __restrict__ b_off,
    const float* __restrict__ w_dcn, const float* __restrict__ b_dcn,
    const float* __restrict__ bn_gamma, const float* __restrict__ bn_beta,
    const float* __restrict__ bn_mean, const float* __restrict__ bn_var,
    float* __restrict__ out)
{
    const int bid  = blockIdx.x;        // 4096
    const int rowg = bid >> 2;          // b*128 + h
    const int qpos = (bid & 3) * 32;
    const int b = rowg >> 7;
    const int h = rowg & 127;
    const int t = threadIdx.x;
    const int wv = t >> 6;
    const int l  = t & 63;
    const int mhalf = wv >> 1;
    const int nhalf = wv & 1;
    const bool act = (l < 49);
    const int ls = act ? l : 0;

    __shared__ uint16_t patch2[16][48];    // de-interleaved bf16 planes, padded-K rows
    __shared__ uint16_t cv[2][16][168];    // conv out bf16 [mhalf][pos][j]
    __shared__ float gate_blk[32];

    const float2* y2b = (const float2*)y2 + (size_t)b * HW;

    // ---- stage plane rows: mean -> patch2[r], max -> patch2[7+r] ----
    for (int i = t; i < 7 * 40; i += 256) {
        const int r  = i / 40;
        const int xi = i % 40;
        const int xx = qpos + xi - 3;
        const int yy = h + r - 3;
        uint32_t mn = 0, mx = 0;
        if (yy >= 0 && yy < HH && xx >= 0 && xx < WW) {
            float2 g2 = y2b[yy * WW + xx];
            mn = f2bf(g2.x);
            mx = f2bf(g2.y);
        }
        patch2[r][xi]     = (uint16_t)mn;
        patch2[7 + r][xi] = (uint16_t)mx;
    }
    // zero pad rows 14,15 (A values there must be non-NaN; B is zero)
    for (int i = t; i < 2 * 48; i += 256)
        patch2[14 + (i / 48)][i % 48] = 0;

    // per-lane (tap) sampling constants
    const float b_dy = b_off[2 * ls];
    const float b_dx = b_off[2 * ls + 1];
    const float b_m  = b_off[98 + ls];
    const float wd0 = w_dcn[ls];
    const float wd1 = w_dcn[49 + ls];
    const int kr = ls / 7;
    const int kc = ls % 7;
    const float bscale = bn_gamma[0] * rsqrtf(bn_var[0] + 1e-5f);
    const float gB = (b_dcn[0] - bn_mean[0]) * bscale + bn_beta[0];

    __syncthreads();

    // ---- MFMA conv: 16 positions (mhalf) x 80 channels (nhalf) ----
    const int m = l & 15;
    const int g = l >> 4;
    const int plocal = mhalf * 16 + m;
    const uint32_t* p32 = (const uint32_t*)&patch2[0][0];

    f32x4 acc[5];
    #pragma unroll
    for (int nn = 0; nn < 5; ++nn) acc[nn] = (f32x4){0.f, 0.f, 0.f, 0.f};

    #pragma unroll
    for (int kt = 0; kt < 4; ++kt) {
        const int grp = kt * 4 + g;
        const int W   = grp * 48 + plocal;         // u16 index of fragment start
        const uint32_t sh8 = (W & 1) ? 16u : 0u;   // byte*8 shift within dword pair
        const uint32_t* dp = p32 + (W >> 1);
        const uint32_t d0 = dp[0], d1 = dp[1], d2 = dp[2], d3 = dp[3], d4 = dp[4];
        union { uint32_t u[4]; bf16x8 v; } af;
        af.u[0] = (uint32_t)(((((uint64_t)d1) << 32) | d0) >> sh8);
        af.u[1] = (uint32_t)(((((uint64_t)d2) << 32) | d1) >> sh8);
        af.u[2] = (uint32_t)(((((uint64_t)d3) << 32) | d2) >> sh8);
        af.u[3] = (uint32_t)(((((uint64_t)d4) << 32) | d3) >> sh8);
        #pragma unroll
        for (int nn = 0; nn < 5; ++nn) {
            const int j = (nhalf * 5 + nn) * 16 + m;
            const bf16x8 bfr = *(const bf16x8*)(Bpre + ((grp * 160 + j) << 3));
            acc[nn] = __builtin_amdgcn_mfma_f32_16x16x32_bf16(af.v, bfr, acc[nn], 0, 0, 0);
        }
    }

    #pragma unroll
    for (int nn = 0; nn < 5; ++nn) {
        #pragma unroll
        for (int q = 0; q < 4; ++q) {
            cv[mhalf][g * 4 + q][(nhalf * 5 + nn) * 16 + m] = (uint16_t)f2bf(acc[nn][q]);
        }
    }
    __syncthreads();

    // ---- sampling: wave wv owns positions [8*wv, 8*wv+8) of the 32 ----
    const uint16_t* cvp = &cv[0][0][0];
    #pragma unroll 4
    for (int pi = 0; pi < 8; ++pi) {
        const int pp = wv * 8 + pi;
        const int posn = qpos + pp;
        const int cbase = pp * 168;

        const float dyv = bf2f(cvp[cbase + ls])      + b_dy;
        const float dxv = bf2f(cvp[cbase + 49 + ls]) + b_dx;
        const float mv  = bf2f(cvp[cbase + 98 + ls]) + b_m;
        const float mk = 1.0f / (1.0f + __expf(-mv));

        const float fy = (float)(h + kr - 3) + dyv;
        const float fx = (float)(posn + kc - 3) + dxv;
        const float fly = floorf(fy), flx = floorf(fx);
        const int iy0 = (int)fly, ix0 = (int)flx;
        const int iy1 = iy0 + 1,  ix1 = ix0 + 1;
        const float wy1 = fy - fly, wy0 = 1.0f - wy1;
        const float wx1 = fx - flx, wx0 = 1.0f - wx1;

        const float vy0 = (iy0 >= 0 && iy0 < HH) ? 1.0f : 0.0f;
        const float vy1 = (iy1 >= 0 && iy1 < HH) ? 1.0f : 0.0f;
        const float vx0 = (ix0 >= 0 && ix0 < WW) ? 1.0f : 0.0f;
        const float vx1 = (ix1 >= 0 && ix1 < WW) ? 1.0f : 0.0f;

        const int cy0 = min(max(iy0, 0), HH - 1) * WW;
        const int cy1 = min(max(iy1, 0), HH - 1) * WW;
        const int cx0 = min(max(ix0, 0), WW - 1);
        const int cx1 = min(max(ix1, 0), WW - 1);

        const float w00 = wy0 * wx0 * vy0 * vx0;
        const float w01 = wy0 * wx1 * vy0 * vx1;
        const float w10 = wy1 * wx0 * vy1 * vx0;
        const float w11 = wy1 * wx1 * vy1 * vx1;

        const float2 g00 = y2b[cy0 + cx0];
        const float2 g01 = y2b[cy0 + cx1];
        const float2 g10 = y2b[cy1 + cx0];
        const float2 g11 = y2b[cy1 + cx1];

        const float v0s = g00.x * w00 + g01.x * w01 + g10.x * w10 + g11.x * w11;
        const float v1s = g00.y * w00 + g01.y * w01 + g10.y * w10 + g11.y * w11;

        float tval = mk * fmaf(v0s, wd0, v1s * wd1);
        tval = act ? tval : 0.0f;

        float ssum = tval;
        #pragma unroll
        for (int off = 1; off < 64; off <<= 1)
            ssum += __shfl_xor(ssum, off);

        if (l == 0) {
            const float o = ssum * bscale + gB;
            gate_blk[pp] = 1.0f / (1.0f + __expf(-o));
        }
    }

    __syncthreads();

    // ---- fused broadcast write: out[b, :, h, qpos:qpos+32] (32 KB/block) ----
    const size_t ob = (size_t)b * CC * HW + (size_t)h * WW + qpos;
    const f32x4* gb4 = (const f32x4*)gate_blk;
    #pragma unroll
    for (int it = 0; it < 8; ++it) {
        const int idx = it * 256 + t;
        const int c   = idx >> 3;
        const int q4  = idx & 7;
        __builtin_nontemporal_store(gb4[q4], (f32x4*)(out + ob + (size_t)c * HW) + q4);
    }
}

extern "C" void kernel_launch(void* const* d_in, const int* in_sizes, int n_in,
                              void* d_out, int out_size, void* d_ws, size_t ws_size,
                              hipStream_t stream) {
    const float* x        = (const float*)d_in[0];
    const float* w_off    = (const float*)d_in[1];
    const float* b_off    = (const float*)d_in[2];
    const float* w_dcn    = (const float*)d_in[3];
    const float* b_dcn    = (const float*)d_in[4];
    const float* bn_gamma = (const float*)d_in[5];
    const float* bn_beta  = (const float*)d_in[6];
    const float* bn_mean  = (const float*)d_in[7];
    const float* bn_var   = (const float*)d_in[8];
    float* out = (float*)d_out;

    float*    y2   = (float*)d_ws;                              // 1 MiB
    uint16_t* Bpre = (uint16_t*)((char*)d_ws + (1 << 20));      // 40 KiB

    reduce_meanmax<<<BB * HH, 512, 0, stream>>>(x, y2, w_off, Bpre);
    deform_gate<<<4 * BB * HH, 256, 0, stream>>>(y2, Bpre, b_off, w_dcn, b_dcn,
                                                 bn_gamma, bn_beta, bn_mean, bn_var,
                                                 out);
}

// Round 18
// 67.626 us; speedup vs baseline: 13.8258x; 1.0221x over previous
//
#include <hip/hip_runtime.h>
#include <cstdint>

#define BB 8
#define CC 256
#define HH 128
#define WW 128
#define HW (HH * WW)

typedef __attribute__((ext_vector_type(8))) short bf16x8;
typedef __attribute__((ext_vector_type(4))) float f32x4;

// round-to-nearest-even f32 -> bf16 (low 16 bits)
__device__ __forceinline__ uint32_t f2bf(float f) {
    uint32_t u = __float_as_uint(f);
    return (u + 0x7FFFu + ((u >> 16) & 1u)) >> 16;
}
__device__ __forceinline__ float bf2f(uint32_t u) {
    return __uint_as_float(u << 16);
}

// ---------------------------------------------------------------------------
// Kernel A: per-position channel mean & max of x -> y2 (B, H*W, 2) float2.
// Folds the B-fragment pre-pack (20 elements per block, threads 0..19).
// Bpre layout [grp][j][e] (grp = ci*7+r): padded-K im2col order; e==7 and
// grp>=14 are ZERO (kill A-side pad garbage: finite*0 = 0).
// ---------------------------------------------------------------------------
__global__ __launch_bounds__(512) void reduce_meanmax(const float* __restrict__ x,
                                                      float* __restrict__ y2,
                                                      const float* __restrict__ w_off,
                                                      uint16_t* __restrict__ Bpre) {
    const int bh = blockIdx.x;
    const int b  = bh >> 7;
    const int h  = bh & 127;
    const int t  = threadIdx.x;

    // ---- folded prep_B: 1024 blocks x 20 = 20480 = 16*160*8 ----
    if (t < 20) {
        const int idx = bh * 20 + t;
        const int e   = idx & 7;
        const int t1  = idx >> 3;
        const int j   = t1 % 160;
        const int grp = t1 / 160;          // 0..15
        uint16_t v = 0;
        if (grp < 14 && e < 7 && j < 147) {
            const int ci = grp / 7, r = grp % 7;
            const int ch = (j < 49) ? (2 * j) : ((j < 98) ? (2 * (j - 49) + 1) : j);
            v = (uint16_t)f2bf(w_off[(size_t)ch * 98 + ci * 49 + r * 7 + e]);
        }
        Bpre[idx] = v;
    }

    const int wq = t & 31;       // float4 column: w = wq*4
    const int cg = t >> 5;       // channel group 0..15 (16 channels each)
    const float* xb = x + ((size_t)(b * CC + cg * 16) * HH + h) * WW;

    float4 s = make_float4(0.f, 0.f, 0.f, 0.f);
    float4 m = make_float4(-INFINITY, -INFINITY, -INFINITY, -INFINITY);
    #pragma unroll 4
    for (int i = 0; i < 16; ++i) {
        float4 v = ((const float4*)(xb + (size_t)i * HW))[wq];
        s.x += v.x; s.y += v.y; s.z += v.z; s.w += v.w;
        m.x = fmaxf(m.x, v.x); m.y = fmaxf(m.y, v.y);
        m.z = fmaxf(m.z, v.z); m.w = fmaxf(m.w, v.w);
    }

    __shared__ float4 ls[16][32];
    __shared__ float4 lm[16][32];
    ls[cg][wq] = s;
    lm[cg][wq] = m;
    __syncthreads();

    if (t < 32) {
        float4 S = ls[0][t];
        float4 M = lm[0][t];
        #pragma unroll
        for (int g = 1; g < 16; ++g) {
            float4 a = ls[g][t];
            float4 c = lm[g][t];
            S.x += a.x; S.y += a.y; S.z += a.z; S.w += a.w;
            M.x = fmaxf(M.x, c.x); M.y = fmaxf(M.y, c.y);
            M.z = fmaxf(M.z, c.z); M.w = fmaxf(M.w, c.w);
        }
        const float inv = 1.0f / 256.0f;
        float4 o0 = make_float4(S.x * inv, M.x, S.y * inv, M.y);
        float4 o1 = make_float4(S.z * inv, M.z, S.w * inv, M.w);
        float4* yo = (float4*)(y2 + ((size_t)b * HW + (size_t)h * WW) * 2);
        yo[2 * t]     = o0;
        yo[2 * t + 1] = o1;
    }
}

// ---------------------------------------------------------------------------
// Kernel B: gate compute + fused broadcast write. Grid = 4096 blocks (one per
// quarter-row = 32 positions), 256 threads = 4 waves.
// r18: (1) XCD-chunk bid swizzle (each XCD owns one batch's 512 contiguous
// blocks -> y2 row reuse and halo gathers are XCD-L2-local);
// (2) sampling in 2 batches of 4 positions: all 16 gathers issued before
// consumption, 4 interleaved shfl-reduce chains (was 8 serial iterations of
// gather->6-dependent-shfl).
// Lessons kept: no min-waves hint (r3/r4/r6 spills); no inter-block sync
// (r13); 4-wave/256-thread split (r15); NT stores (r16 neutral); de-interleaved
// padded-K A-fragments (r17); inline-bounds staging (r14).
// ---------------------------------------------------------------------------
__global__ __launch_bounds__(256) void deform_gate(
    const float* __restrict__ y2, const uint16_t* __restrict__ Bpre,
    const float* __restrict__ b_off,
    const float* __restrict__ w_dcn, const float* __restrict__ b_dcn,
    const float* __restrict__ bn_gamma, const float* __restrict__ bn_beta,
    const float* __restrict__ bn_mean, const float* __restrict__ bn_var,
    float* __restrict__ out)
{
    // bijective XCD-chunk swizzle (4096 % 8 == 0)
    const int bid  = (blockIdx.x & 7) * 512 + (blockIdx.x >> 3);
    const int rowg = bid >> 2;          // b*128 + h
    const int qpos = (bid & 3) * 32;
    const int b = rowg >> 7;
    const int h = rowg & 127;
    const int t = threadIdx.x;
    const int wv = t >> 6;
    const int l  = t & 63;
    const int mhalf = wv >> 1;
    const int nhalf = wv & 1;
    const bool act = (l < 49);
    const int ls = act ? l : 0;

    __shared__ uint16_t patch2[16][48];    // de-interleaved bf16 planes, padded-K rows
    __shared__ uint16_t cv[2][16][168];    // conv out bf16 [mhalf][pos][j]
    __shared__ float gate_blk[32];

    const float2* y2b = (const float2*)y2 + (size_t)b * HW;

    // ---- stage plane rows: mean -> patch2[r], max -> patch2[7+r] ----
    for (int i = t; i < 7 * 40; i += 256) {
        const int r  = i / 40;
        const int xi = i % 40;
        const int xx = qpos + xi - 3;
        const int yy = h + r - 3;
        uint32_t mn = 0, mx = 0;
        if (yy >= 0 && yy < HH && xx >= 0 && xx < WW) {
            float2 g2 = y2b[yy * WW + xx];
            mn = f2bf(g2.x);
            mx = f2bf(g2.y);
        }
        patch2[r][xi]     = (uint16_t)mn;
        patch2[7 + r][xi] = (uint16_t)mx;
    }
    // zero pad rows 14,15
    for (int i = t; i < 2 * 48; i += 256)
        patch2[14 + (i / 48)][i % 48] = 0;

    // per-lane (tap) sampling constants
    const float b_dy = b_off[2 * ls];
    const float b_dx = b_off[2 * ls + 1];
    const float b_m  = b_off[98 + ls];
    const float wd0 = w_dcn[ls];
    const float wd1 = w_dcn[49 + ls];
    const int kr = ls / 7;
    const int kc = ls % 7;
    const float bscale = bn_gamma[0] * rsqrtf(bn_var[0] + 1e-5f);
    const float gB = (b_dcn[0] - bn_mean[0]) * bscale + bn_beta[0];

    __syncthreads();

    // ---- MFMA conv: 16 positions (mhalf) x 80 channels (nhalf) ----
    const int m = l & 15;
    const int g = l >> 4;
    const int plocal = mhalf * 16 + m;
    const uint32_t* p32 = (const uint32_t*)&patch2[0][0];

    f32x4 acc[5];
    #pragma unroll
    for (int nn = 0; nn < 5; ++nn) acc[nn] = (f32x4){0.f, 0.f, 0.f, 0.f};

    #pragma unroll
    for (int kt = 0; kt < 4; ++kt) {
        const int grp = kt * 4 + g;
        const int W   = grp * 48 + plocal;         // u16 index of fragment start
        const uint32_t sh8 = (W & 1) ? 16u : 0u;
        const uint32_t* dp = p32 + (W >> 1);
        const uint32_t d0 = dp[0], d1 = dp[1], d2 = dp[2], d3 = dp[3], d4 = dp[4];
        union { uint32_t u[4]; bf16x8 v; } af;
        af.u[0] = (uint32_t)(((((uint64_t)d1) << 32) | d0) >> sh8);
        af.u[1] = (uint32_t)(((((uint64_t)d2) << 32) | d1) >> sh8);
        af.u[2] = (uint32_t)(((((uint64_t)d3) << 32) | d2) >> sh8);
        af.u[3] = (uint32_t)(((((uint64_t)d4) << 32) | d3) >> sh8);
        #pragma unroll
        for (int nn = 0; nn < 5; ++nn) {
            const int j = (nhalf * 5 + nn) * 16 + m;
            const bf16x8 bfr = *(const bf16x8*)(Bpre + ((grp * 160 + j) << 3));
            acc[nn] = __builtin_amdgcn_mfma_f32_16x16x32_bf16(af.v, bfr, acc[nn], 0, 0, 0);
        }
    }

    #pragma unroll
    for (int nn = 0; nn < 5; ++nn) {
        #pragma unroll
        for (int q = 0; q < 4; ++q) {
            cv[mhalf][g * 4 + q][(nhalf * 5 + nn) * 16 + m] = (uint16_t)f2bf(acc[nn][q]);
        }
    }
    __syncthreads();

    // ---- sampling: wave wv owns positions [8*wv, 8*wv+8); 2 batches of 4:
    //      issue all 16 gathers, then consume, then 4 interleaved reductions ----
    const uint16_t* cvp = &cv[0][0][0];
    #pragma unroll 1
    for (int hb = 0; hb < 2; ++hb) {
        const int p0 = wv * 8 + hb * 4;

        float mkv[4], w00[4], w01[4], w10[4], w11[4];
        float2 g00[4], g01[4], g10[4], g11[4];

        #pragma unroll
        for (int pi = 0; pi < 4; ++pi) {
            const int pp = p0 + pi;
            const int cbase = pp * 168;

            const float dyv = bf2f(cvp[cbase + ls])      + b_dy;
            const float dxv = bf2f(cvp[cbase + 49 + ls]) + b_dx;
            const float mv  = bf2f(cvp[cbase + 98 + ls]) + b_m;
            mkv[pi] = 1.0f / (1.0f + __expf(-mv));

            const float fy = (float)(h + kr - 3) + dyv;
            const float fx = (float)(qpos + pp + kc - 3) + dxv;
            const float fly = floorf(fy), flx = floorf(fx);
            const int iy0 = (int)fly, ix0 = (int)flx;
            const int iy1 = iy0 + 1,  ix1 = ix0 + 1;
            const float wy1 = fy - fly, wy0 = 1.0f - wy1;
            const float wx1 = fx - flx, wx0 = 1.0f - wx1;

            const float vy0 = (iy0 >= 0 && iy0 < HH) ? 1.0f : 0.0f;
            const float vy1 = (iy1 >= 0 && iy1 < HH) ? 1.0f : 0.0f;
            const float vx0 = (ix0 >= 0 && ix0 < WW) ? 1.0f : 0.0f;
            const float vx1 = (ix1 >= 0 && ix1 < WW) ? 1.0f : 0.0f;

            const int cy0 = min(max(iy0, 0), HH - 1) * WW;
            const int cy1 = min(max(iy1, 0), HH - 1) * WW;
            const int cx0 = min(max(ix0, 0), WW - 1);
            const int cx1 = min(max(ix1, 0), WW - 1);

            w00[pi] = wy0 * wx0 * vy0 * vx0;
            w01[pi] = wy0 * wx1 * vy0 * vx1;
            w10[pi] = wy1 * wx0 * vy1 * vx0;
            w11[pi] = wy1 * wx1 * vy1 * vx1;

            g00[pi] = y2b[cy0 + cx0];
            g01[pi] = y2b[cy0 + cx1];
            g10[pi] = y2b[cy1 + cx0];
            g11[pi] = y2b[cy1 + cx1];
        }

        float tv[4];
        #pragma unroll
        for (int pi = 0; pi < 4; ++pi) {
            const float v0s = g00[pi].x * w00[pi] + g01[pi].x * w01[pi]
                            + g10[pi].x * w10[pi] + g11[pi].x * w11[pi];
            const float v1s = g00[pi].y * w00[pi] + g01[pi].y * w01[pi]
                            + g10[pi].y * w10[pi] + g11[pi].y * w11[pi];
            float tval = mkv[pi] * fmaf(v0s, wd0, v1s * wd1);
            tv[pi] = act ? tval : 0.0f;
        }

        // 4 interleaved 6-step reductions
        #pragma unroll
        for (int off = 1; off < 64; off <<= 1) {
            #pragma unroll
            for (int pi = 0; pi < 4; ++pi)
                tv[pi] += __shfl_xor(tv[pi], off);
        }

        if (l == 0) {
            #pragma unroll
            for (int pi = 0; pi < 4; ++pi) {
                const float o = tv[pi] * bscale + gB;
                gate_blk[p0 + pi] = 1.0f / (1.0f + __expf(-o));
            }
        }
    }

    __syncthreads();

    // ---- fused broadcast write: out[b, :, h, qpos:qpos+32] (32 KB/block) ----
    const size_t ob = (size_t)b * CC * HW + (size_t)h * WW + qpos;
    const f32x4* gb4 = (const f32x4*)gate_blk;
    #pragma unroll
    for (int it = 0; it < 8; ++it) {
        const int idx = it * 256 + t;
        const int c   = idx >> 3;
        const int q4  = idx & 7;
        __builtin_nontemporal_store(gb4[q4], (f32x4*)(out + ob + (size_t)c * HW) + q4);
    }
}

extern "C" void kernel_launch(void* const* d_in, const int* in_sizes, int n_in,
                              void* d_out, int out_size, void* d_ws, size_t ws_size,
                              hipStream_t stream) {
    const float* x        = (const float*)d_in[0];
    const float* w_off    = (const float*)d_in[1];
    const float* b_off    = (const float*)d_in[2];
    const float* w_dcn    = (const float*)d_in[3];
    const float* b_dcn    = (const float*)d_in[4];
    const float* bn_gamma = (const float*)d_in[5];
    const float* bn_beta  = (const float*)d_in[6];
    const float* bn_mean  = (const float*)d_in[7];
    const float* bn_var   = (const float*)d_in[8];
    float* out = (float*)d_out;

    float*    y2   = (float*)d_ws;                              // 1 MiB
    uint16_t* Bpre = (uint16_t*)((char*)d_ws + (1 << 20));      // 40 KiB

    reduce_meanmax<<<BB * HH, 512, 0, stream>>>(x, y2, w_off, Bpre);
    deform_gate<<<4 * BB * HH, 256, 0, stream>>>(y2, Bpre, b_off, w_dcn, b_dcn,
                                                 bn_gamma, bn_beta, bn_mean, bn_var,
                                                 out);
}